// Round 3
// baseline (1062.690 us; speedup 1.0000x reference)
//
#include <hip/hip_runtime.h>
#include <math.h>

#define NN 12288
#define DD 128
#define EPSF 1e-7f
#define MAXNORM (1.0f - 1e-3f)
#define CSPLIT 4
#define CCOLS (NN / CSPLIT)      /* 3072 columns per block */
#define CSTEPS (CCOLS / 128)     /* 24 steps of 128 columns */
#define BITS_U64_PER_ROW (NN / 64)   /* 192 */

typedef __attribute__((ext_vector_type(8))) short short8_t;
typedef __attribute__((ext_vector_type(4))) float float4_t;
typedef unsigned short ushort_t;
typedef unsigned long long u64_t;

__device__ __forceinline__ unsigned short f2bf(float f) {
    unsigned int u = __builtin_bit_cast(unsigned int, f);
    unsigned int r = u + 0x7FFFu + ((u >> 16) & 1u);
    return (unsigned short)(r >> 16);
}

// ---------------- Kernel 1: per-row prep ----------------
__global__ __launch_bounds__(128) void prep_kernel(
    const float* __restrict__ x, const float* __restrict__ a,
    ushort_t* __restrict__ xtb,
    float* __restrict__ wh1, float* __restrict__ wh2)
{
    const int r = blockIdx.x;
    const int t = threadIdx.x;
    const float xv = x[r * DD + t];
    const float a1 = a[t];
    const float a2 = a[DD + t];
    float s0 = xv * xv, s1 = xv * a1, s2 = xv * a2;
    #pragma unroll
    for (int o = 32; o > 0; o >>= 1) {
        s0 += __shfl_xor(s0, o);
        s1 += __shfl_xor(s1, o);
        s2 += __shfl_xor(s2, o);
    }
    __shared__ float red[6];
    const int w = t >> 6;
    if ((t & 63) == 0) { red[w * 3 + 0] = s0; red[w * 3 + 1] = s1; red[w * 3 + 2] = s2; }
    __syncthreads();
    const float sumsq = red[0] + red[3];
    const float d1    = red[1] + red[4];
    const float d2    = red[2] + red[5];
    const float nraw  = sqrtf(sumsq);
    const float nrm   = fminf(fmaxf(nraw, EPSF), 1.0f - EPSF);
    const float scale = atanhf(nrm) / nrm;
    xtb[(size_t)r * DD + t] = f2bf(xv * scale);
    if (t == 0) {
        wh1[r] = scale * d1;
        wh2[r] = scale * d2;
    }
}

// ---------------- Kernel 2: build xtB in MFMA-B-fragment-linear layout ----
// chunk C (32 j), dt: 1 KB block; element (lane, e) = xt[C*32+(lane>>4)*8+e][dt*16+(lane&15)]
__global__ __launch_bounds__(256) void swizzle_kernel(
    const ushort_t* __restrict__ xtb, ushort_t* __restrict__ xtB)
{
    __shared__ ushort_t raw[32 * 136];
    const int C = blockIdx.x;
    const int t = threadIdx.x;
    #pragma unroll
    for (int p = 0; p < 2; ++p) {
        const int idx = p * 256 + t;
        const int j = idx >> 4, cell = idx & 15;
        const uint4 v = *(const uint4*)(xtb + (size_t)(C * 32 + j) * DD + cell * 8);
        *(uint4*)&raw[j * 136 + cell * 8] = v;
    }
    __syncthreads();
    #pragma unroll
    for (int p = 0; p < 2; ++p) {
        const int oc = p * 256 + t;       // 0..511 = dt*64 + lane
        const int dt = oc >> 6;
        const int l6 = oc & 63;
        const int l15 = l6 & 15, q = l6 >> 4;
        short8_t v;
        #pragma unroll
        for (int e = 0; e < 8; ++e)
            v[e] = (short)raw[(q * 8 + e) * 136 + dt * 16 + l15];
        *(short8_t*)(xtB + (size_t)C * 4096 + oc * 8) = v;
    }
}

// ---------------- Kernel 2b: compress adj (int32 0/1) into a bitmask ----
// 604 MB -> 18.9 MB, read perfectly contiguously (256 B per wave-inst).
__global__ __launch_bounds__(256) void bitify_kernel(
    const int* __restrict__ adj, u64_t* __restrict__ bits)
{
    const int i = blockIdx.x;                 // row
    const int w = threadIdx.x >> 6;           // wave 0..3
    const int lane = threadIdx.x & 63;
    const int* rp = adj + (size_t)i * NN;
    #pragma unroll 8
    for (int k = 0; k < BITS_U64_PER_ROW / 4; ++k) {   // 48 iters per wave
        const int word = w * (BITS_U64_PER_ROW / 4) + k;
        const int v = rp[word * 64 + lane];
        const u64_t b = __ballot(v > 0);
        if (lane == 0) bits[(size_t)i * BITS_U64_PER_ROW + word] = b;
    }
}

// ---------------- Kernel 3: flash-style MFMA attention (bitmask adj) ----
// grid (192, 4), 3 blocks/CU. Wave owns 16 rows x 3072 cols. B fragments
// software-pipelined at distance 1 kc through named register buffers
// BfA/BfB: per kc-unit, ISSUE next kc's 8 loads -> compute exp/af (VALU,
// independent of B) -> MFMA on the buffer issued one kc earlier. This
// batches the L2 loads instead of the load->mfma->load->mfma serial chain.
__global__ __launch_bounds__(256, 3) void attn_kernel(
    const u64_t* __restrict__ bits,
    const ushort_t* __restrict__ xtB,
    const float* __restrict__ wh1, const float* __restrict__ wh2,
    float* __restrict__ pout, float* __restrict__ plsum)
{
    __shared__ __align__(16) float wh2_lds[CCOLS];   // 12 KB

    const int t = threadIdx.x;
    const int w = t >> 6, lane = t & 63;
    const int l15 = lane & 15, quad = lane >> 4;
    const int cy = blockIdx.y;
    const int jcol0 = cy * CCOLS;
    const int rowbase = blockIdx.x * 64 + w * 16;    // wave's 16 rows

    #pragma unroll
    for (int m = 0; m < CCOLS / 256; ++m)
        wh2_lds[m * 256 + t] = wh2[jcol0 + m * 256 + t];
    const float wh1i = wh1[rowbase + l15];
    __syncthreads();

    // uint4 = 128 bits = one step's columns for this lane's row
    const uint4* bitp = (const uint4*)bits
                      + (size_t)(rowbase + l15) * (NN / 128) + cy * CSTEPS;
    const ushort_t* Bbase = xtB + (size_t)(jcol0 >> 5) * 4096 + (size_t)lane * 8;

    float4_t acc[8];
    #pragma unroll
    for (int dt = 0; dt < 8; ++dt) acc[dt] = (float4_t)0.0f;
    float lsum = 0.0f;

    short8_t BfA[8], BfB[8];

    auto load_B = [&](int u, short8_t (&Bf)[8]) {
        const ushort_t* Bp = Bbase + (size_t)u * 4096;
        #pragma unroll
        for (int dt = 0; dt < 8; ++dt)
            Bf[dt] = *(const short8_t*)(Bp + dt * 512);
    };

    auto kc_unit = [&](unsigned word, int st, int kc, short8_t (&Bcur)[8]) {
        const unsigned wq = (word >> (quad * 8)) & 0xFFu;
        const int wbase = st * 128 + kc * 32 + quad * 8;
        const float4 Wa = *(const float4*)&wh2_lds[wbase];
        const float4 Wb = *(const float4*)&wh2_lds[wbase + 4];
        const float u0 = wh1i + Wa.x, u1 = wh1i + Wa.y;
        const float u2 = wh1i + Wa.z, u3 = wh1i + Wa.w;
        const float u4 = wh1i + Wb.x, u5 = wh1i + Wb.y;
        const float u6 = wh1i + Wb.z, u7 = wh1i + Wb.w;
        const float p0 = (wq & 1u)   ? __expf(fmaxf(u0, 0.2f * u0)) : 0.0f;
        const float p1 = (wq & 2u)   ? __expf(fmaxf(u1, 0.2f * u1)) : 0.0f;
        const float p2 = (wq & 4u)   ? __expf(fmaxf(u2, 0.2f * u2)) : 0.0f;
        const float p3 = (wq & 8u)   ? __expf(fmaxf(u3, 0.2f * u3)) : 0.0f;
        const float p4 = (wq & 16u)  ? __expf(fmaxf(u4, 0.2f * u4)) : 0.0f;
        const float p5 = (wq & 32u)  ? __expf(fmaxf(u5, 0.2f * u5)) : 0.0f;
        const float p6 = (wq & 64u)  ? __expf(fmaxf(u6, 0.2f * u6)) : 0.0f;
        const float p7 = (wq & 128u) ? __expf(fmaxf(u7, 0.2f * u7)) : 0.0f;
        lsum += ((p0 + p1) + (p2 + p3)) + ((p4 + p5) + (p6 + p7));
        short8_t af;
        af[0] = (short)f2bf(p0); af[1] = (short)f2bf(p1);
        af[2] = (short)f2bf(p2); af[3] = (short)f2bf(p3);
        af[4] = (short)f2bf(p4); af[5] = (short)f2bf(p5);
        af[6] = (short)f2bf(p6); af[7] = (short)f2bf(p7);
        #pragma unroll
        for (int dt = 0; dt < 8; ++dt)
            acc[dt] = __builtin_amdgcn_mfma_f32_16x16x32_bf16(af, Bcur[dt], acc[dt], 0, 0, 0);
    };

    // One step = 4 kc-units; alternate BfA/BfB so each kc consumes the
    // buffer whose loads were issued one kc earlier.
    auto do_step = [&](const uint4 Mj, const int st, const bool skipLastLoad) {
        const int u = st * 4;
        load_B(u + 1, BfB); kc_unit(Mj.x, st, 0, BfA);
        load_B(u + 2, BfA); kc_unit(Mj.y, st, 1, BfB);
        load_B(u + 3, BfB); kc_unit(Mj.z, st, 2, BfA);
        if (!skipLastLoad) load_B(u + 4, BfA);
        kc_unit(Mj.w, st, 3, BfB);
    };

    uint4 M0 = bitp[0], M1 = bitp[1], M2 = bitp[2];
    load_B(0, BfA);

    #pragma unroll 1
    for (int st0 = 0; st0 < CSTEPS - 3; st0 += 3) {   // st0 = 0,3,...,18
        const uint4 mA = M0; M0 = bitp[st0 + 3];
        do_step(mA, st0, false);
        const uint4 mB = M1; M1 = bitp[st0 + 4];
        do_step(mB, st0 + 1, false);
        const uint4 mC = M2; M2 = bitp[st0 + 5];
        do_step(mC, st0 + 2, false);
    }
    // peeled final group: st = 21, 22, 23 (no mask prefetch, last B guarded)
    do_step(M0, CSTEPS - 3, false);
    do_step(M1, CSTEPS - 2, false);
    do_step(M2, CSTEPS - 1, true);

    // ---- epilogue: one partial per column-quarter ----
    float v = lsum;
    v += __shfl_xor(v, 16);
    v += __shfl_xor(v, 32);
    if (quad == 0) plsum[(size_t)cy * NN + rowbase + l15] = v;
    #pragma unroll
    for (int dt = 0; dt < 8; ++dt)
        #pragma unroll
        for (int reg = 0; reg < 4; ++reg)
            pout[((size_t)cy * NN + rowbase + quad * 4 + reg) * DD + dt * 16 + l15]
                = acc[dt][reg];
}

// ---------------- Kernel 4: combine partials + normalize + expmap0 + proj ----
__global__ __launch_bounds__(128) void reduce_kernel(
    const float* __restrict__ pout, const float* __restrict__ plsum,
    float* __restrict__ out)
{
    const int i = blockIdx.x;
    const int t = threadIdx.x;
    float v = 0.0f;
    #pragma unroll
    for (int s = 0; s < CSPLIT; ++s) v += pout[((size_t)s * NN + i) * DD + t];
    float ls = 0.0f;
    #pragma unroll
    for (int s = 0; s < CSPLIT; ++s) ls += plsum[(size_t)s * NN + i];
    v /= ls;
    float ss = v * v;
    #pragma unroll
    for (int o = 1; o < 64; o <<= 1) ss += __shfl_xor(ss, o);
    __shared__ float r2[2];
    if ((t & 63) == 0) r2[t >> 6] = ss;
    __syncthreads();
    const float total = r2[0] + r2[1];
    const float nraw = sqrtf(total);
    const float nv   = fmaxf(nraw, EPSF);
    const float th   = tanhf(nv);
    const float ysc  = th / nv;
    const float nyr  = ysc * nraw;
    const float ny   = fmaxf(nyr, EPSF);
    const float psc  = (ny > MAXNORM) ? (MAXNORM / ny) : 1.0f;
    const float os   = ysc * psc;
    out[(size_t)i * DD + t] = v * os;
}

extern "C" void kernel_launch(void* const* d_in, const int* in_sizes, int n_in,
                              void* d_out, int out_size, void* d_ws, size_t ws_size,
                              hipStream_t stream) {
    const float* x   = (const float*)d_in[0];
    const int*   adj = (const int*)d_in[1];
    const float* a   = (const float*)d_in[2];
    float* out = (float*)d_out;

    // ---- workspace layout (~50 MB; ws is ~2.4 GB) ----
    char* ws = (char*)d_ws;
    ushort_t* xtb = (ushort_t*)ws;  ws += (size_t)NN * DD * sizeof(ushort_t);
    ushort_t* xtB = (ushort_t*)ws;  ws += (size_t)NN * DD * sizeof(ushort_t);
    float* wh1 = (float*)ws;        ws += NN * sizeof(float);
    float* wh2 = (float*)ws;        ws += NN * sizeof(float);
    float* plsum = (float*)ws;      ws += (size_t)CSPLIT * NN * sizeof(float);
    float* pout  = (float*)ws;      ws += (size_t)CSPLIT * NN * DD * sizeof(float);
    u64_t* bits  = (u64_t*)ws;

    prep_kernel<<<NN, 128, 0, stream>>>(x, a, xtb, wh1, wh2);
    swizzle_kernel<<<NN / 32, 256, 0, stream>>>(xtb, xtB);
    bitify_kernel<<<NN, 256, 0, stream>>>(adj, bits);
    attn_kernel<<<dim3(NN / 64, CSPLIT), 256, 0, stream>>>(
        bits, xtB, wh1, wh2, pout, plsum);
    reduce_kernel<<<NN, 128, 0, stream>>>(pout, plsum, out);
}

// Round 4
// 1059.408 us; speedup vs baseline: 1.0031x; 1.0031x over previous
//
#include <hip/hip_runtime.h>
#include <math.h>

#define NN 12288
#define DD 128
#define EPSF 1e-7f
#define MAXNORM (1.0f - 1e-3f)
#define CSPLIT 4
#define CCOLS (NN / CSPLIT)      /* 3072 columns per block */
#define CSTEPS (CCOLS / 128)     /* 24 steps of 128 columns */
#define BITS_U64_PER_ROW (NN / 64)   /* 192 */

typedef __attribute__((ext_vector_type(8))) short short8_t;
typedef __attribute__((ext_vector_type(4))) float float4_t;
typedef unsigned short ushort_t;
typedef unsigned long long u64_t;

__device__ __forceinline__ unsigned short f2bf(float f) {
    unsigned int u = __builtin_bit_cast(unsigned int, f);
    unsigned int r = u + 0x7FFFu + ((u >> 16) & 1u);
    return (unsigned short)(r >> 16);
}

// ---------------- Kernel 1: per-row prep ----------------
__global__ __launch_bounds__(128) void prep_kernel(
    const float* __restrict__ x, const float* __restrict__ a,
    ushort_t* __restrict__ xtb,
    float* __restrict__ wh1, float* __restrict__ wh2)
{
    const int r = blockIdx.x;
    const int t = threadIdx.x;
    const float xv = x[r * DD + t];
    const float a1 = a[t];
    const float a2 = a[DD + t];
    float s0 = xv * xv, s1 = xv * a1, s2 = xv * a2;
    #pragma unroll
    for (int o = 32; o > 0; o >>= 1) {
        s0 += __shfl_xor(s0, o);
        s1 += __shfl_xor(s1, o);
        s2 += __shfl_xor(s2, o);
    }
    __shared__ float red[6];
    const int w = t >> 6;
    if ((t & 63) == 0) { red[w * 3 + 0] = s0; red[w * 3 + 1] = s1; red[w * 3 + 2] = s2; }
    __syncthreads();
    const float sumsq = red[0] + red[3];
    const float d1    = red[1] + red[4];
    const float d2    = red[2] + red[5];
    const float nraw  = sqrtf(sumsq);
    const float nrm   = fminf(fmaxf(nraw, EPSF), 1.0f - EPSF);
    const float scale = atanhf(nrm) / nrm;
    xtb[(size_t)r * DD + t] = f2bf(xv * scale);
    if (t == 0) {
        wh1[r] = scale * d1;
        wh2[r] = scale * d2;
    }
}

// ---------------- Kernel 2: build xtB in MFMA-B-fragment-linear layout ----
// chunk C (32 j), dt: 1 KB block; element (lane, e) = xt[C*32+(lane>>4)*8+e][dt*16+(lane&15)]
__global__ __launch_bounds__(256) void swizzle_kernel(
    const ushort_t* __restrict__ xtb, ushort_t* __restrict__ xtB)
{
    __shared__ ushort_t raw[32 * 136];
    const int C = blockIdx.x;
    const int t = threadIdx.x;
    #pragma unroll
    for (int p = 0; p < 2; ++p) {
        const int idx = p * 256 + t;
        const int j = idx >> 4, cell = idx & 15;
        const uint4 v = *(const uint4*)(xtb + (size_t)(C * 32 + j) * DD + cell * 8);
        *(uint4*)&raw[j * 136 + cell * 8] = v;
    }
    __syncthreads();
    #pragma unroll
    for (int p = 0; p < 2; ++p) {
        const int oc = p * 256 + t;       // 0..511 = dt*64 + lane
        const int dt = oc >> 6;
        const int l6 = oc & 63;
        const int l15 = l6 & 15, q = l6 >> 4;
        short8_t v;
        #pragma unroll
        for (int e = 0; e < 8; ++e)
            v[e] = (short)raw[(q * 8 + e) * 136 + dt * 16 + l15];
        *(short8_t*)(xtB + (size_t)C * 4096 + oc * 8) = v;
    }
}

// ---------------- Kernel 2b: compress adj (int32 0/1) into a bitmask ----
// 604 MB -> 18.9 MB, read perfectly contiguously (256 B per wave-inst).
__global__ __launch_bounds__(256) void bitify_kernel(
    const int* __restrict__ adj, u64_t* __restrict__ bits)
{
    const int i = blockIdx.x;                 // row
    const int w = threadIdx.x >> 6;           // wave 0..3
    const int lane = threadIdx.x & 63;
    const int* rp = adj + (size_t)i * NN;
    #pragma unroll 8
    for (int k = 0; k < BITS_U64_PER_ROW / 4; ++k) {   // 48 iters per wave
        const int word = w * (BITS_U64_PER_ROW / 4) + k;
        const int v = rp[word * 64 + lane];
        const u64_t b = __ballot(v > 0);
        if (lane == 0) bits[(size_t)i * BITS_U64_PER_ROW + word] = b;
    }
}

// ---------------- Kernel 3: MFMA attention, bitmask adj + LDS-staged B ----
// grid (192, 4), 2 blocks/CU. Per step (128 cols): issue 8 dwordx4/thread
// staging loads for step st+1 -> compute step st entirely from LDS
// (conflict-free ds_read_b128) -> ds_write staged regs -> ONE barrier.
// Main-loop global ops: the batched stage loads (consumed a full step
// later, latency fully hidden) and one uint4 mask load. No register-
// consumed L2 chains anywhere.
__global__ __launch_bounds__(256, 2) void attn_kernel(
    const u64_t* __restrict__ bits,
    const ushort_t* __restrict__ xtB,
    const float* __restrict__ wh1, const float* __restrict__ wh2,
    float* __restrict__ pout, float* __restrict__ plsum)
{
    __shared__ __align__(16) ushort_t Bl0[128 * DD];   // 32 KB (even steps)
    __shared__ __align__(16) ushort_t Bl1[128 * DD];   // 32 KB (odd steps)
    __shared__ __align__(16) float wh2_lds[CCOLS];     // 12 KB

    const int t = threadIdx.x;
    const int w = t >> 6, lane = t & 63;
    const int l15 = lane & 15, quad = lane >> 4;
    const int cy = blockIdx.y;
    const int jcol0 = cy * CCOLS;
    const int rowbase = blockIdx.x * 64 + w * 16;    // wave's 16 rows

    #pragma unroll
    for (int m = 0; m < CCOLS / 256; ++m)
        wh2_lds[m * 256 + t] = wh2[jcol0 + m * 256 + t];
    const float wh1i = wh1[rowbase + l15];

    // uint4 = 128 bits = one step's columns for this lane's row
    const uint4* bitp = (const uint4*)bits
                      + (size_t)(rowbase + l15) * (NN / 128) + cy * CSTEPS;
    // step st = 32 KB contiguous at xtB + (jcol0>>5)*4096 ushorts + st*2048 uint4
    const uint4* Bsrc = (const uint4*)(xtB + (size_t)(jcol0 >> 5) * 4096);

    float4_t acc[8];
    #pragma unroll
    for (int dt = 0; dt < 8; ++dt) acc[dt] = (float4_t)0.0f;
    float lsum = 0.0f;

    uint4 sr[8];   // staging registers (static indexing only)

    auto stage_load = [&](int st) {
        const uint4* sp = Bsrc + (size_t)st * 2048 + t;
        #pragma unroll
        for (int r = 0; r < 8; ++r) sr[r] = sp[r * 256];
    };
    auto stage_write = [&](ushort_t* buf) {
        uint4* d = (uint4*)buf + t;
        #pragma unroll
        for (int r = 0; r < 8; ++r) d[r * 256] = sr[r];
    };

    auto compute = [&](int st, const ushort_t* buf, const uint4 M) {
        #pragma unroll
        for (int kc = 0; kc < 4; ++kc) {
            const unsigned word = (kc == 0) ? M.x : (kc == 1) ? M.y
                                : (kc == 2) ? M.z : M.w;
            const unsigned wq = (word >> (quad * 8)) & 0xFFu;
            const int wbase = st * 128 + kc * 32 + quad * 8;
            const float4 Wa = *(const float4*)&wh2_lds[wbase];
            const float4 Wb = *(const float4*)&wh2_lds[wbase + 4];
            const float u0 = wh1i + Wa.x, u1 = wh1i + Wa.y;
            const float u2 = wh1i + Wa.z, u3 = wh1i + Wa.w;
            const float u4 = wh1i + Wb.x, u5 = wh1i + Wb.y;
            const float u6 = wh1i + Wb.z, u7 = wh1i + Wb.w;
            const float p0 = (wq & 1u)   ? __expf(fmaxf(u0, 0.2f * u0)) : 0.0f;
            const float p1 = (wq & 2u)   ? __expf(fmaxf(u1, 0.2f * u1)) : 0.0f;
            const float p2 = (wq & 4u)   ? __expf(fmaxf(u2, 0.2f * u2)) : 0.0f;
            const float p3 = (wq & 8u)   ? __expf(fmaxf(u3, 0.2f * u3)) : 0.0f;
            const float p4 = (wq & 16u)  ? __expf(fmaxf(u4, 0.2f * u4)) : 0.0f;
            const float p5 = (wq & 32u)  ? __expf(fmaxf(u5, 0.2f * u5)) : 0.0f;
            const float p6 = (wq & 64u)  ? __expf(fmaxf(u6, 0.2f * u6)) : 0.0f;
            const float p7 = (wq & 128u) ? __expf(fmaxf(u7, 0.2f * u7)) : 0.0f;
            lsum += ((p0 + p1) + (p2 + p3)) + ((p4 + p5) + (p6 + p7));
            short8_t af;
            af[0] = (short)f2bf(p0); af[1] = (short)f2bf(p1);
            af[2] = (short)f2bf(p2); af[3] = (short)f2bf(p3);
            af[4] = (short)f2bf(p4); af[5] = (short)f2bf(p5);
            af[6] = (short)f2bf(p6); af[7] = (short)f2bf(p7);
            const ushort_t* Bp = buf + kc * 4096 + lane * 8;
            #pragma unroll
            for (int dt = 0; dt < 8; ++dt) {
                const short8_t Bf = *(const short8_t*)(Bp + dt * 512);
                acc[dt] = __builtin_amdgcn_mfma_f32_16x16x32_bf16(af, Bf, acc[dt], 0, 0, 0);
            }
        }
    };

    // ---- prologue: stage step 0 into Bl0 ----
    stage_load(0);
    stage_write(Bl0);
    uint4 Mc = bitp[0];
    __syncthreads();

    // ---- main loop: unroll-by-2 for static double-buffer selection ----
    #pragma unroll 1
    for (int st0 = 0; st0 < CSTEPS; st0 += 2) {
        // even step: read Bl0, prefetch st0+1 into Bl1
        if (st0 + 1 < CSTEPS) stage_load(st0 + 1);
        const uint4 Mn1 = (st0 + 1 < CSTEPS) ? bitp[st0 + 1] : Mc;
        compute(st0, Bl0, Mc);
        Mc = Mn1;
        if (st0 + 1 < CSTEPS) stage_write(Bl1);
        __syncthreads();
        if (st0 + 1 >= CSTEPS) break;
        // odd step: read Bl1, prefetch st0+2 into Bl0
        if (st0 + 2 < CSTEPS) stage_load(st0 + 2);
        const uint4 Mn2 = (st0 + 2 < CSTEPS) ? bitp[st0 + 2] : Mc;
        compute(st0 + 1, Bl1, Mc);
        Mc = Mn2;
        if (st0 + 2 < CSTEPS) stage_write(Bl0);
        __syncthreads();
    }

    // ---- epilogue: one partial per column-quarter ----
    float v = lsum;
    v += __shfl_xor(v, 16);
    v += __shfl_xor(v, 32);
    if (quad == 0) plsum[(size_t)cy * NN + rowbase + l15] = v;
    #pragma unroll
    for (int dt = 0; dt < 8; ++dt)
        #pragma unroll
        for (int reg = 0; reg < 4; ++reg)
            pout[((size_t)cy * NN + rowbase + quad * 4 + reg) * DD + dt * 16 + l15]
                = acc[dt][reg];
}

// ---------------- Kernel 4: combine partials + normalize + expmap0 + proj ----
__global__ __launch_bounds__(128) void reduce_kernel(
    const float* __restrict__ pout, const float* __restrict__ plsum,
    float* __restrict__ out)
{
    const int i = blockIdx.x;
    const int t = threadIdx.x;
    float v = 0.0f;
    #pragma unroll
    for (int s = 0; s < CSPLIT; ++s) v += pout[((size_t)s * NN + i) * DD + t];
    float ls = 0.0f;
    #pragma unroll
    for (int s = 0; s < CSPLIT; ++s) ls += plsum[(size_t)s * NN + i];
    v /= ls;
    float ss = v * v;
    #pragma unroll
    for (int o = 1; o < 64; o <<= 1) ss += __shfl_xor(ss, o);
    __shared__ float r2[2];
    if ((t & 63) == 0) r2[t >> 6] = ss;
    __syncthreads();
    const float total = r2[0] + r2[1];
    const float nraw = sqrtf(total);
    const float nv   = fmaxf(nraw, EPSF);
    const float th   = tanhf(nv);
    const float ysc  = th / nv;
    const float nyr  = ysc * nraw;
    const float ny   = fmaxf(nyr, EPSF);
    const float psc  = (ny > MAXNORM) ? (MAXNORM / ny) : 1.0f;
    const float os   = ysc * psc;
    out[(size_t)i * DD + t] = v * os;
}

extern "C" void kernel_launch(void* const* d_in, const int* in_sizes, int n_in,
                              void* d_out, int out_size, void* d_ws, size_t ws_size,
                              hipStream_t stream) {
    const float* x   = (const float*)d_in[0];
    const int*   adj = (const int*)d_in[1];
    const float* a   = (const float*)d_in[2];
    float* out = (float*)d_out;

    // ---- workspace layout (~50 MB; ws is ~2.4 GB) ----
    char* ws = (char*)d_ws;
    ushort_t* xtb = (ushort_t*)ws;  ws += (size_t)NN * DD * sizeof(ushort_t);
    ushort_t* xtB = (ushort_t*)ws;  ws += (size_t)NN * DD * sizeof(ushort_t);
    float* wh1 = (float*)ws;        ws += NN * sizeof(float);
    float* wh2 = (float*)ws;        ws += NN * sizeof(float);
    float* plsum = (float*)ws;      ws += (size_t)CSPLIT * NN * sizeof(float);
    float* pout  = (float*)ws;      ws += (size_t)CSPLIT * NN * DD * sizeof(float);
    u64_t* bits  = (u64_t*)ws;

    prep_kernel<<<NN, 128, 0, stream>>>(x, a, xtb, wh1, wh2);
    swizzle_kernel<<<NN / 32, 256, 0, stream>>>(xtb, xtB);
    bitify_kernel<<<NN, 256, 0, stream>>>(adj, bits);
    attn_kernel<<<dim3(NN / 64, CSPLIT), 256, 0, stream>>>(
        bits, xtB, wh1, wh2, pout, plsum);
    reduce_kernel<<<NN, 128, 0, stream>>>(pout, plsum, out);
}

// Round 5
// 951.430 us; speedup vs baseline: 1.1169x; 1.1135x over previous
//
#include <hip/hip_runtime.h>
#include <math.h>

#define NN 12288
#define DD 128
#define EPSF 1e-7f
#define MAXNORM (1.0f - 1e-3f)
#define CSPLIT 4
#define CCOLS (NN / CSPLIT)      /* 3072 columns per block */
#define CSTEPS (CCOLS / 128)     /* 24 steps of 128 columns */

typedef __attribute__((ext_vector_type(8))) short short8_t;
typedef __attribute__((ext_vector_type(4))) float float4_t;
typedef unsigned short ushort_t;

__device__ __forceinline__ unsigned short f2bf(float f) {
    unsigned int u = __builtin_bit_cast(unsigned int, f);
    unsigned int r = u + 0x7FFFu + ((u >> 16) & 1u);
    return (unsigned short)(r >> 16);
}

// ---------------- Kernel 1: per-row prep ----------------
__global__ __launch_bounds__(128) void prep_kernel(
    const float* __restrict__ x, const float* __restrict__ a,
    ushort_t* __restrict__ xtb,
    float* __restrict__ wh1, float* __restrict__ wh2)
{
    const int r = blockIdx.x;
    const int t = threadIdx.x;
    const float xv = x[r * DD + t];
    const float a1 = a[t];
    const float a2 = a[DD + t];
    float s0 = xv * xv, s1 = xv * a1, s2 = xv * a2;
    #pragma unroll
    for (int o = 32; o > 0; o >>= 1) {
        s0 += __shfl_xor(s0, o);
        s1 += __shfl_xor(s1, o);
        s2 += __shfl_xor(s2, o);
    }
    __shared__ float red[6];
    const int w = t >> 6;
    if ((t & 63) == 0) { red[w * 3 + 0] = s0; red[w * 3 + 1] = s1; red[w * 3 + 2] = s2; }
    __syncthreads();
    const float sumsq = red[0] + red[3];
    const float d1    = red[1] + red[4];
    const float d2    = red[2] + red[5];
    const float nraw  = sqrtf(sumsq);
    const float nrm   = fminf(fmaxf(nraw, EPSF), 1.0f - EPSF);
    const float scale = atanhf(nrm) / nrm;
    xtb[(size_t)r * DD + t] = f2bf(xv * scale);
    if (t == 0) {
        wh1[r] = scale * d1;
        wh2[r] = scale * d2;
    }
}

// ---------------- Kernel 2: build xtB in MFMA-B-fragment-linear layout ----
// chunk C (32 j), dt: 1 KB block; element (lane, e) = xt[C*32+(lane>>4)*8+e][dt*16+(lane&15)]
__global__ __launch_bounds__(256) void swizzle_kernel(
    const ushort_t* __restrict__ xtb, ushort_t* __restrict__ xtB)
{
    __shared__ ushort_t raw[32 * 136];
    const int C = blockIdx.x;
    const int t = threadIdx.x;
    #pragma unroll
    for (int p = 0; p < 2; ++p) {
        const int idx = p * 256 + t;
        const int j = idx >> 4, cell = idx & 15;
        const uint4 v = *(const uint4*)(xtb + (size_t)(C * 32 + j) * DD + cell * 8);
        *(uint4*)&raw[j * 136 + cell * 8] = v;
    }
    __syncthreads();
    #pragma unroll
    for (int p = 0; p < 2; ++p) {
        const int oc = p * 256 + t;       // 0..511 = dt*64 + lane
        const int dt = oc >> 6;
        const int l6 = oc & 63;
        const int l15 = l6 & 15, q = l6 >> 4;
        short8_t v;
        #pragma unroll
        for (int e = 0; e < 8; ++e)
            v[e] = (short)raw[(q * 8 + e) * 136 + dt * 16 + l15];
        *(short8_t*)(xtB + (size_t)C * 4096 + oc * 8) = v;
    }
}

// ---------------- Kernel 3: flash MFMA attention, adj-direct, LDS-staged B --
// grid (192, 4), 2 blocks/CU (76 KB LDS). NO bitify pre-pass: adj is read
// directly (the one unavoidable 604 MB stream, coalesced int4 pattern that
// measured at the HBM roofline in round 0). Per step (128 cols): issue
// next step's B staging loads (8 dwordx4/thread) + next step's adj loads
// (8 int4/lane, register double-buffer) -> compute current step from LDS
// -> ds_write staged B -> ONE barrier. acc lives across all 24 steps;
// partials are CSPLIT=4 (25 MB) instead of round-0's 24 slabs (151 MB).
__global__ __launch_bounds__(256, 2) void attn_kernel(
    const int* __restrict__ adj,
    const ushort_t* __restrict__ xtB,
    const float* __restrict__ wh1, const float* __restrict__ wh2,
    float* __restrict__ pout, float* __restrict__ plsum)
{
    __shared__ __align__(16) ushort_t Bl0[128 * DD];   // 32 KB (even steps)
    __shared__ __align__(16) ushort_t Bl1[128 * DD];   // 32 KB (odd steps)
    __shared__ __align__(16) float wh2_lds[CCOLS];     // 12 KB

    const int t = threadIdx.x;
    const int w = t >> 6, lane = t & 63;
    const int l15 = lane & 15, quad = lane >> 4;
    const int cy = blockIdx.y;
    const int jcol0 = cy * CCOLS;
    const int rowbase = blockIdx.x * 64 + w * 16;    // wave's 16 rows

    #pragma unroll
    for (int m = 0; m < CCOLS / 256; ++m)
        wh2_lds[m * 256 + t] = wh2[jcol0 + m * 256 + t];
    const float wh1i = wh1[rowbase + l15];

    const int* adj_lane = adj + (size_t)(rowbase + l15) * NN + jcol0 + quad * 8;
    // step st = 32 KB contiguous at xtB + (jcol0>>5)*4096 ushorts + st*2048 uint4
    const uint4* Bsrc = (const uint4*)(xtB + (size_t)(jcol0 >> 5) * 4096);

    float4_t acc[8];
    #pragma unroll
    for (int dt = 0; dt < 8; ++dt) acc[dt] = (float4_t)0.0f;
    float lsum = 0.0f;

    uint4 sr[8];            // B staging registers (static indexing only)
    int4 Aa[8], Ab[8];      // adj double buffer (static indexing only)

    auto stage_load = [&](int st) {
        const uint4* sp = Bsrc + (size_t)st * 2048 + t;
        #pragma unroll
        for (int r = 0; r < 8; ++r) sr[r] = sp[r * 256];
    };
    auto stage_write = [&](ushort_t* buf) {
        uint4* d = (uint4*)buf + t;
        #pragma unroll
        for (int r = 0; r < 8; ++r) d[r * 256] = sr[r];
    };
    auto adj_load = [&](int st, int4 (&A)[8]) {
        const int* bp = adj_lane + st * 128;
        #pragma unroll
        for (int kc = 0; kc < 4; ++kc) {
            A[kc * 2 + 0] = *(const int4*)(bp + kc * 32);
            A[kc * 2 + 1] = *(const int4*)(bp + kc * 32 + 4);
        }
    };

    auto compute = [&](int st, const ushort_t* buf, const int4 (&A)[8]) {
        #pragma unroll
        for (int kc = 0; kc < 4; ++kc) {
            const int4 Av = A[kc * 2 + 0], Ac = A[kc * 2 + 1];
            const int wbase = st * 128 + kc * 32 + quad * 8;
            const float4 Wa = *(const float4*)&wh2_lds[wbase];
            const float4 Wb = *(const float4*)&wh2_lds[wbase + 4];
            const float u0 = wh1i + Wa.x, u1 = wh1i + Wa.y;
            const float u2 = wh1i + Wa.z, u3 = wh1i + Wa.w;
            const float u4 = wh1i + Wb.x, u5 = wh1i + Wb.y;
            const float u6 = wh1i + Wb.z, u7 = wh1i + Wb.w;
            const float p0 = (Av.x > 0) ? __expf(fmaxf(u0, 0.2f * u0)) : 0.0f;
            const float p1 = (Av.y > 0) ? __expf(fmaxf(u1, 0.2f * u1)) : 0.0f;
            const float p2 = (Av.z > 0) ? __expf(fmaxf(u2, 0.2f * u2)) : 0.0f;
            const float p3 = (Av.w > 0) ? __expf(fmaxf(u3, 0.2f * u3)) : 0.0f;
            const float p4 = (Ac.x > 0) ? __expf(fmaxf(u4, 0.2f * u4)) : 0.0f;
            const float p5 = (Ac.y > 0) ? __expf(fmaxf(u5, 0.2f * u5)) : 0.0f;
            const float p6 = (Ac.z > 0) ? __expf(fmaxf(u6, 0.2f * u6)) : 0.0f;
            const float p7 = (Ac.w > 0) ? __expf(fmaxf(u7, 0.2f * u7)) : 0.0f;
            lsum += ((p0 + p1) + (p2 + p3)) + ((p4 + p5) + (p6 + p7));
            short8_t af;
            af[0] = (short)f2bf(p0); af[1] = (short)f2bf(p1);
            af[2] = (short)f2bf(p2); af[3] = (short)f2bf(p3);
            af[4] = (short)f2bf(p4); af[5] = (short)f2bf(p5);
            af[6] = (short)f2bf(p6); af[7] = (short)f2bf(p7);
            const ushort_t* Bp = buf + kc * 4096 + lane * 8;
            #pragma unroll
            for (int dt = 0; dt < 8; ++dt) {
                const short8_t Bf = *(const short8_t*)(Bp + dt * 512);
                acc[dt] = __builtin_amdgcn_mfma_f32_16x16x32_bf16(af, Bf, acc[dt], 0, 0, 0);
            }
        }
    };

    // ---- prologue: stage step 0 (B -> Bl0, adj -> Aa) ----
    stage_load(0);
    stage_write(Bl0);
    adj_load(0, Aa);
    __syncthreads();

    // ---- main loop: unroll-by-2 for static double-buffer selection ----
    #pragma unroll 1
    for (int st0 = 0; st0 < CSTEPS; st0 += 2) {
        // even step: read Bl0/Aa, prefetch st0+1 into Bl1/Ab
        if (st0 + 1 < CSTEPS) { stage_load(st0 + 1); adj_load(st0 + 1, Ab); }
        compute(st0, Bl0, Aa);
        if (st0 + 1 < CSTEPS) stage_write(Bl1);
        __syncthreads();
        if (st0 + 1 >= CSTEPS) break;
        // odd step: read Bl1/Ab, prefetch st0+2 into Bl0/Aa
        if (st0 + 2 < CSTEPS) { stage_load(st0 + 2); adj_load(st0 + 2, Aa); }
        compute(st0 + 1, Bl1, Ab);
        if (st0 + 2 < CSTEPS) stage_write(Bl0);
        __syncthreads();
    }

    // ---- epilogue: one partial per column-quarter ----
    float v = lsum;
    v += __shfl_xor(v, 16);
    v += __shfl_xor(v, 32);
    if (quad == 0) plsum[(size_t)cy * NN + rowbase + l15] = v;
    #pragma unroll
    for (int dt = 0; dt < 8; ++dt)
        #pragma unroll
        for (int reg = 0; reg < 4; ++reg)
            pout[((size_t)cy * NN + rowbase + quad * 4 + reg) * DD + dt * 16 + l15]
                = acc[dt][reg];
}

// ---------------- Kernel 4: combine partials + normalize + expmap0 + proj ----
__global__ __launch_bounds__(128) void reduce_kernel(
    const float* __restrict__ pout, const float* __restrict__ plsum,
    float* __restrict__ out)
{
    const int i = blockIdx.x;
    const int t = threadIdx.x;
    float v = 0.0f;
    #pragma unroll
    for (int s = 0; s < CSPLIT; ++s) v += pout[((size_t)s * NN + i) * DD + t];
    float ls = 0.0f;
    #pragma unroll
    for (int s = 0; s < CSPLIT; ++s) ls += plsum[(size_t)s * NN + i];
    v /= ls;
    float ss = v * v;
    #pragma unroll
    for (int o = 1; o < 64; o <<= 1) ss += __shfl_xor(ss, o);
    __shared__ float r2[2];
    if ((t & 63) == 0) r2[t >> 6] = ss;
    __syncthreads();
    const float total = r2[0] + r2[1];
    const float nraw = sqrtf(total);
    const float nv   = fmaxf(nraw, EPSF);
    const float th   = tanhf(nv);
    const float ysc  = th / nv;
    const float nyr  = ysc * nraw;
    const float ny   = fmaxf(nyr, EPSF);
    const float psc  = (ny > MAXNORM) ? (MAXNORM / ny) : 1.0f;
    const float os   = ysc * psc;
    out[(size_t)i * DD + t] = v * os;
}

extern "C" void kernel_launch(void* const* d_in, const int* in_sizes, int n_in,
                              void* d_out, int out_size, void* d_ws, size_t ws_size,
                              hipStream_t stream) {
    const float* x   = (const float*)d_in[0];
    const int*   adj = (const int*)d_in[1];
    const float* a   = (const float*)d_in[2];
    float* out = (float*)d_out;

    // ---- workspace layout (~31 MB; ws is ~2.4 GB) ----
    char* ws = (char*)d_ws;
    ushort_t* xtb = (ushort_t*)ws;  ws += (size_t)NN * DD * sizeof(ushort_t);
    ushort_t* xtB = (ushort_t*)ws;  ws += (size_t)NN * DD * sizeof(ushort_t);
    float* wh1 = (float*)ws;        ws += NN * sizeof(float);
    float* wh2 = (float*)ws;        ws += NN * sizeof(float);
    float* plsum = (float*)ws;      ws += (size_t)CSPLIT * NN * sizeof(float);
    float* pout  = (float*)ws;

    prep_kernel<<<NN, 128, 0, stream>>>(x, a, xtb, wh1, wh2);
    swizzle_kernel<<<NN / 32, 256, 0, stream>>>(xtb, xtB);
    attn_kernel<<<dim3(NN / 64, CSPLIT), 256, 0, stream>>>(
        adj, xtB, wh1, wh2, pout, plsum);
    reduce_kernel<<<NN, 128, 0, stream>>>(pout, plsum, out);
}